// Round 1
// baseline (657.875 us; speedup 1.0000x reference)
//
#include <hip/hip_runtime.h>
#include <hip/hip_bf16.h>

// CrossAttentionLayer on MI355X (gfx950), round 1.
// Pipeline: [weights fp32->bf16^T] [LN x, ctx] [GEMM Q,K,V] [V->Vt] [attn]
//           [GEMM Wo + bo + x -> x2(f32)] [LN x2] [GEMM W1+b1+SiLU] [GEMM W2+b2+x2 -> out]
// All GEMMs: C = A[M,K](bf16) * Bt[N,K](bf16)^T, 128x128 tile, BK=64,
// global_load_lds(16B) staging with XOR-swizzled LDS (pre-swizzled source).

typedef __bf16 bf16x8 __attribute__((ext_vector_type(8)));
typedef float f32x4 __attribute__((ext_vector_type(4)));

#define DEV static __device__ __forceinline__

DEV short f2bf(float x) {  // RNE float->bf16
  union { float f; unsigned u; } c; c.f = x;
  unsigned r = c.u + 0x7fffu + ((c.u >> 16) & 1u);
  return (short)(r >> 16);
}

DEV void gload_lds16(const void* g, void* l) {
  __builtin_amdgcn_global_load_lds((__attribute__((address_space(1))) void*)g,
                                   (__attribute__((address_space(3))) void*)l, 16, 0, 0);
}

// ---------------------------------------------------------------- transpose
// in [R][C] fp32 -> out [C][R] bf16
__launch_bounds__(256, 4)
__global__ void transpose_f32_bf16(const float* __restrict__ in, short* __restrict__ outT,
                                   int R, int C) {
  __shared__ float t[32][33];
  const int c0 = blockIdx.x * 32, r0 = blockIdx.y * 32;
  const int tx = threadIdx.x, ty = threadIdx.y;
#pragma unroll
  for (int i = 0; i < 4; ++i)
    t[ty + 8 * i][tx] = in[(size_t)(r0 + ty + 8 * i) * C + (c0 + tx)];
  __syncthreads();
#pragma unroll
  for (int i = 0; i < 4; ++i)
    outT[(size_t)(c0 + ty + 8 * i) * R + (r0 + tx)] = f2bf(t[tx][ty + 8 * i]);
}

// V [B*2048][1024](bf16) -> Vt [bh][64][2048](bf16)
__launch_bounds__(256, 4)
__global__ void transpose_v(const short* __restrict__ V, short* __restrict__ Vt) {
  __shared__ short t[32][33];
  const int m0 = blockIdx.x * 32;
  const int d0 = blockIdx.y * 32;
  const int bh = blockIdx.z;
  const int b = bh >> 4, h = bh & 15;
  const int tx = threadIdx.x, ty = threadIdx.y;
#pragma unroll
  for (int i = 0; i < 4; ++i)
    t[ty + 8 * i][tx] = V[((size_t)b * 2048 + m0 + ty + 8 * i) * 1024 + h * 64 + d0 + tx];
  __syncthreads();
#pragma unroll
  for (int i = 0; i < 4; ++i)
    Vt[((size_t)bh * 64 + d0 + ty + 8 * i) * 2048 + (m0 + tx)] = t[tx][ty + 8 * i];
}

// ---------------------------------------------------------------- layernorm
// 1024 cols, fp32 in -> bf16 out
__launch_bounds__(256, 4)
__global__ void ln_kernel(const float* __restrict__ in, const float* __restrict__ g,
                          const float* __restrict__ b, short* __restrict__ out) {
  const int row = blockIdx.x;
  const int tid = threadIdx.x;
  const float4 v = ((const float4*)(in + (size_t)row * 1024))[tid];
  float s = v.x + v.y + v.z + v.w;
  float s2 = v.x * v.x + v.y * v.y + v.z * v.z + v.w * v.w;
#pragma unroll
  for (int off = 1; off < 64; off <<= 1) {
    s += __shfl_xor(s, off);
    s2 += __shfl_xor(s2, off);
  }
  __shared__ float ps[4], pq[4];
  const int w = tid >> 6, lane = tid & 63;
  if (lane == 0) { ps[w] = s; pq[w] = s2; }
  __syncthreads();
  s = ps[0] + ps[1] + ps[2] + ps[3];
  s2 = pq[0] + pq[1] + pq[2] + pq[3];
  const float mu = s * (1.f / 1024.f);
  const float rs = rsqrtf(s2 * (1.f / 1024.f) - mu * mu + 1e-5f);
  const float4 gg = ((const float4*)g)[tid];
  const float4 bb = ((const float4*)b)[tid];
  short4 o4;
  o4.x = f2bf((v.x - mu) * rs * gg.x + bb.x);
  o4.y = f2bf((v.y - mu) * rs * gg.y + bb.y);
  o4.z = f2bf((v.z - mu) * rs * gg.z + bb.z);
  o4.w = f2bf((v.w - mu) * rs * gg.w + bb.w);
  ((short4*)(out + (size_t)row * 1024))[tid] = o4;
}

// ---------------------------------------------------------------- GEMM
enum { EPI_Q = 0, EPI_PLAIN = 1, EPI_BIAS_RESID_F32 = 2, EPI_BIAS_SILU = 3 };

template <int EPI>
__launch_bounds__(256, 2)
__global__ void gemm_bt(const short* __restrict__ A, const short* __restrict__ Bt,
                        int N, int K, const float* __restrict__ bias,
                        const float* __restrict__ resid, float scale,
                        short* __restrict__ outb, float* __restrict__ outf) {
  __shared__ short Al[128 * 64];
  __shared__ short Bl[128 * 64];
  const int tid = threadIdx.x;
  const int lane = tid & 63, w = tid >> 6;
  const int wrow = w >> 1, wcol = w & 1;
  const int lg = lane >> 4, lr = lane & 15;
  const int row0 = blockIdx.y * 128, col0 = blockIdx.x * 128;

  f32x4 acc[4][4] = {};

  const int sr = w * 32 + (lane >> 3);  // staging row (+ i*8)
  // source col-byte, pre-swizzled so linear LDS + swizzled read line up
  const int scb = ((lane & 7) * 16) ^ (((lane >> 3) & 7) << 4);
  const int fswz = (lr & 7) << 4;

  for (int kk = 0; kk < K; kk += 64) {
    __syncthreads();
#pragma unroll
    for (int i = 0; i < 4; ++i) {
      const int r = sr + i * 8;
      gload_lds16((const char*)(A + (size_t)(row0 + r) * K + kk) + scb,
                  (char*)Al + (size_t)(w * 32 + i * 8) * 128);
      gload_lds16((const char*)(Bt + (size_t)(col0 + r) * K + kk) + scb,
                  (char*)Bl + (size_t)(w * 32 + i * 8) * 128);
    }
    __syncthreads();
#pragma unroll
    for (int ks = 0; ks < 2; ++ks) {
      bf16x8 af[4], bfr[4];
#pragma unroll
      for (int mi = 0; mi < 4; ++mi) {
        const int r = wrow * 64 + mi * 16 + lr;
        af[mi] = *(const bf16x8*)((const char*)Al + r * 128 + ((ks * 64 + lg * 16) ^ fswz));
      }
#pragma unroll
      for (int ni = 0; ni < 4; ++ni) {
        const int c = wcol * 64 + ni * 16 + lr;
        bfr[ni] = *(const bf16x8*)((const char*)Bl + c * 128 + ((ks * 64 + lg * 16) ^ fswz));
      }
#pragma unroll
      for (int mi = 0; mi < 4; ++mi)
#pragma unroll
        for (int ni = 0; ni < 4; ++ni)
          acc[mi][ni] = __builtin_amdgcn_mfma_f32_16x16x32_bf16(af[mi], bfr[ni], acc[mi][ni], 0, 0, 0);
    }
  }
  // epilogue: C[row][col], row = row0+wrow*64+mi*16+lg*4+r, col = col0+wcol*64+ni*16+lr
#pragma unroll
  for (int mi = 0; mi < 4; ++mi) {
#pragma unroll
    for (int ni = 0; ni < 4; ++ni) {
      const int cg = col0 + wcol * 64 + ni * 16 + lr;
#pragma unroll
      for (int r = 0; r < 4; ++r) {
        const int rg = row0 + wrow * 64 + mi * 16 + lg * 4 + r;
        const size_t idx = (size_t)rg * N + cg;
        const float v = acc[mi][ni][r];
        if constexpr (EPI == EPI_Q) {
          outb[idx] = f2bf(v * scale);
        } else if constexpr (EPI == EPI_PLAIN) {
          outb[idx] = f2bf(v);
        } else if constexpr (EPI == EPI_BIAS_RESID_F32) {
          outf[idx] = v + bias[cg] + resid[idx];
        } else {  // bias + SiLU -> bf16
          const float u = v + bias[cg];
          outb[idx] = f2bf(u / (1.f + __expf(-u)));
        }
      }
    }
  }
}

// ---------------------------------------------------------------- attention
// grid (N/128, B*H); 4 waves/block, 32 q-rows per wave, KV tiles of 128.
// Swapped QK^T: St = mfma(K_frag, Q_frag) -> lane holds q=lane&15 column.
// Q pre-scaled by 1/8*log2(e); softmax in exp2 domain.
__launch_bounds__(256, 2)
__global__ void attn_kernel(const short* __restrict__ Qg, const short* __restrict__ Kg,
                            const short* __restrict__ Vtg, short* __restrict__ AO) {
  __shared__ short Pl[4][32 * 128];  // per-wave P buffer, swizzled rows of 256B
  const int tid = threadIdx.x;
  const int lane = tid & 63, w = tid >> 6;
  const int lg = lane >> 4, lr = lane & 15;
  const int bh = blockIdx.y;
  const int b = bh >> 4, h = bh & 15;
  const int q0 = blockIdx.x * 128 + w * 32;

  bf16x8 qf[2][2];
#pragma unroll
  for (int qb = 0; qb < 2; ++qb) {
    const short* qp = Qg + ((size_t)b * 2048 + q0 + qb * 16 + lr) * 1024 + h * 64 + lg * 8;
    qf[qb][0] = *(const bf16x8*)qp;
    qf[qb][1] = *(const bf16x8*)(qp + 32);
  }
  const short* Kp = Kg + (size_t)b * 2048 * 1024 + h * 64;
  const short* Vp = Vtg + (size_t)bh * 64 * 2048;

  f32x4 acc[2][4] = {};
  float m_run[2] = {-1e30f, -1e30f};
  float l_run[2] = {0.f, 0.f};
  char* myP = (char*)&Pl[w][0];
  const int swz = (lr & 7) << 4;

  for (int kv0 = 0; kv0 < 2048; kv0 += 128) {
    f32x4 st[8][2];
#pragma unroll
    for (int t = 0; t < 8; ++t) {
      const short* kp = Kp + (size_t)(kv0 + t * 16 + lr) * 1024 + lg * 8;
      const bf16x8 kf0 = *(const bf16x8*)kp;
      const bf16x8 kf1 = *(const bf16x8*)(kp + 32);
#pragma unroll
      for (int qb = 0; qb < 2; ++qb) {
        f32x4 z = {};
        z = __builtin_amdgcn_mfma_f32_16x16x32_bf16(kf0, qf[qb][0], z, 0, 0, 0);
        z = __builtin_amdgcn_mfma_f32_16x16x32_bf16(kf1, qf[qb][1], z, 0, 0, 0);
        st[t][qb] = z;
      }
    }
#pragma unroll
    for (int qb = 0; qb < 2; ++qb) {
      float smax = -1e30f;
#pragma unroll
      for (int t = 0; t < 8; ++t)
#pragma unroll
        for (int r = 0; r < 4; ++r) smax = fmaxf(smax, st[t][qb][r]);
      smax = fmaxf(smax, __shfl_xor(smax, 16));
      smax = fmaxf(smax, __shfl_xor(smax, 32));
      const float mnew = fmaxf(m_run[qb], smax);
      const float alpha = __builtin_amdgcn_exp2f(m_run[qb] - mnew);
      m_run[qb] = mnew;
      float rsum = 0.f;
#pragma unroll
      for (int t = 0; t < 8; ++t) {
        const float p0 = __builtin_amdgcn_exp2f(st[t][qb][0] - mnew);
        const float p1 = __builtin_amdgcn_exp2f(st[t][qb][1] - mnew);
        const float p2 = __builtin_amdgcn_exp2f(st[t][qb][2] - mnew);
        const float p3 = __builtin_amdgcn_exp2f(st[t][qb][3] - mnew);
        rsum += (p0 + p1) + (p2 + p3);
        short4 pk;
        pk.x = f2bf(p0); pk.y = f2bf(p1); pk.z = f2bf(p2); pk.w = f2bf(p3);
        *(short4*)(myP + (qb * 16 + lr) * 256 + ((t * 32 + lg * 8) ^ swz)) = pk;
      }
      rsum += __shfl_xor(rsum, 16);
      rsum += __shfl_xor(rsum, 32);
      l_run[qb] = l_run[qb] * alpha + rsum;
      float ar[4];
#pragma unroll
      for (int r = 0; r < 4; ++r) ar[r] = __shfl(alpha, lg * 4 + r);
#pragma unroll
      for (int dt = 0; dt < 4; ++dt)
#pragma unroll
        for (int r = 0; r < 4; ++r) acc[qb][dt][r] *= ar[r];
    }
    // PV: O += P @ V   (P from LDS, V from global Vt — L2-resident)
#pragma unroll
    for (int c = 0; c < 4; ++c) {
      bf16x8 pf[2];
      pf[0] = *(const bf16x8*)(myP + (size_t)(lr)*256 + ((c * 64 + lg * 16) ^ swz));
      pf[1] = *(const bf16x8*)(myP + (size_t)(16 + lr) * 256 + ((c * 64 + lg * 16) ^ swz));
#pragma unroll
      for (int dt = 0; dt < 4; ++dt) {
        const bf16x8 vf = *(const bf16x8*)(Vp + (size_t)(dt * 16 + lr) * 2048 + kv0 + c * 32 + lg * 8);
        acc[0][dt] = __builtin_amdgcn_mfma_f32_16x16x32_bf16(pf[0], vf, acc[0][dt], 0, 0, 0);
        acc[1][dt] = __builtin_amdgcn_mfma_f32_16x16x32_bf16(pf[1], vf, acc[1][dt], 0, 0, 0);
      }
    }
  }
#pragma unroll
  for (int qb = 0; qb < 2; ++qb) {
    const float linv = 1.f / l_run[qb];
    float lv[4];
#pragma unroll
    for (int r = 0; r < 4; ++r) lv[r] = __shfl(linv, lg * 4 + r);
#pragma unroll
    for (int dt = 0; dt < 4; ++dt)
#pragma unroll
      for (int r = 0; r < 4; ++r)
        AO[((size_t)b * 2048 + q0 + qb * 16 + lg * 4 + r) * 1024 + h * 64 + dt * 16 + lr] =
            f2bf(acc[qb][dt][r] * lv[r]);
  }
}

// ---------------------------------------------------------------- launch
extern "C" void kernel_launch(void* const* d_in, const int* in_sizes, int n_in,
                              void* d_out, int out_size, void* d_ws, size_t ws_size,
                              hipStream_t stream) {
  const float* x   = (const float*)d_in[0];
  const float* ctx = (const float*)d_in[1];
  const float* Wq  = (const float*)d_in[2];
  const float* Wk  = (const float*)d_in[3];
  const float* Wv  = (const float*)d_in[4];
  const float* Wo  = (const float*)d_in[5];
  const float* bo  = (const float*)d_in[6];
  const float* g_q = (const float*)d_in[7];
  const float* b_q = (const float*)d_in[8];
  const float* g_k = (const float*)d_in[9];
  const float* b_k = (const float*)d_in[10];
  const float* g_m = (const float*)d_in[11];
  const float* b_m = (const float*)d_in[12];
  const float* W1  = (const float*)d_in[13];
  const float* b1  = (const float*)d_in[14];
  const float* W2  = (const float*)d_in[15];
  const float* b2  = (const float*)d_in[16];
  float* out = (float*)d_out;

  // workspace carve-up (bf16 buffers as short*)
  short* p = (short*)d_ws;
  short* xn  = p; p += (size_t)8192 * 1024;
  short* cn  = p; p += (size_t)8192 * 1024;
  short* Qb  = p; p += (size_t)8192 * 1024;
  short* Kb  = p; p += (size_t)8192 * 1024;
  short* Vb  = p; p += (size_t)8192 * 1024;
  short* Vts = p; p += (size_t)8192 * 1024;
  short* AO  = p; p += (size_t)8192 * 1024;
  short* hn  = p; p += (size_t)8192 * 1024;
  short* hm  = p; p += (size_t)8192 * 4096;
  short* WqT = p; p += (size_t)1024 * 1024;
  short* WkT = p; p += (size_t)1024 * 1024;
  short* WvT = p; p += (size_t)1024 * 1024;
  short* WoT = p; p += (size_t)1024 * 1024;
  short* W1T = p; p += (size_t)1024 * 4096;
  short* W2T = p; p += (size_t)4096 * 1024;
  float* x2  = (float*)p;  // 8192*1024 fp32

  const dim3 tb(32, 8);
  // weights -> bf16 transposed [out][in]
  transpose_f32_bf16<<<dim3(32, 32), tb, 0, stream>>>(Wq, WqT, 1024, 1024);
  transpose_f32_bf16<<<dim3(32, 32), tb, 0, stream>>>(Wk, WkT, 1024, 1024);
  transpose_f32_bf16<<<dim3(32, 32), tb, 0, stream>>>(Wv, WvT, 1024, 1024);
  transpose_f32_bf16<<<dim3(32, 32), tb, 0, stream>>>(Wo, WoT, 1024, 1024);
  transpose_f32_bf16<<<dim3(128, 32), tb, 0, stream>>>(W1, W1T, 1024, 4096);
  transpose_f32_bf16<<<dim3(32, 128), tb, 0, stream>>>(W2, W2T, 4096, 1024);

  ln_kernel<<<8192, 256, 0, stream>>>(x, g_q, b_q, xn);
  ln_kernel<<<8192, 256, 0, stream>>>(ctx, g_k, b_k, cn);

  // Q scaled by 1/sqrt(64) * log2(e)  (softmax done in exp2 domain)
  const float qscale = 0.125f * 1.44269504088896340736f;
  gemm_bt<EPI_Q><<<dim3(8, 64), 256, 0, stream>>>(xn, WqT, 1024, 1024, nullptr, nullptr, qscale, Qb, nullptr);
  gemm_bt<EPI_PLAIN><<<dim3(8, 64), 256, 0, stream>>>(cn, WkT, 1024, 1024, nullptr, nullptr, 0.f, Kb, nullptr);
  gemm_bt<EPI_PLAIN><<<dim3(8, 64), 256, 0, stream>>>(cn, WvT, 1024, 1024, nullptr, nullptr, 0.f, Vb, nullptr);

  transpose_v<<<dim3(64, 2, 64), tb, 0, stream>>>(Vb, Vts);

  attn_kernel<<<dim3(16, 64), 256, 0, stream>>>(Qb, Kb, Vts, AO);

  gemm_bt<EPI_BIAS_RESID_F32><<<dim3(8, 64), 256, 0, stream>>>(AO, WoT, 1024, 1024, bo, x, 0.f, nullptr, x2);

  ln_kernel<<<8192, 256, 0, stream>>>(x2, g_m, b_m, hn);

  gemm_bt<EPI_BIAS_SILU><<<dim3(32, 64), 256, 0, stream>>>(hn, W1T, 4096, 1024, b1, nullptr, 0.f, hm, nullptr);
  gemm_bt<EPI_BIAS_RESID_F32><<<dim3(8, 64), 256, 0, stream>>>(hm, W2T, 1024, 4096, b2, x2, 0.f, nullptr, out);
}

// Round 2
// 459.272 us; speedup vs baseline: 1.4324x; 1.4324x over previous
//
#include <hip/hip_runtime.h>
#include <hip/hip_bf16.h>

// CrossAttentionLayer on MI355X (gfx950), round 2.
// Round-2 change: attention rewritten — 8 waves/block, KV tiles of 64 staged
// into double-buffered LDS via global_load_lds (pre-swizzled source, T2),
// 2-phase prefetch (T3-min), defer-max (T13), XCD-aware block swizzle (T1).
// GEMM/LN/transpose stages unchanged from round 1.

typedef __bf16 bf16x8 __attribute__((ext_vector_type(8)));
typedef __bf16 bf16x4 __attribute__((ext_vector_type(4)));
typedef float f32x4 __attribute__((ext_vector_type(4)));

#define DEV static __device__ __forceinline__

DEV short f2bf(float x) {  // RNE float->bf16
  union { float f; unsigned u; } c; c.f = x;
  unsigned r = c.u + 0x7fffu + ((c.u >> 16) & 1u);
  return (short)(r >> 16);
}

DEV void gload_lds16(const void* g, void* l) {
  __builtin_amdgcn_global_load_lds((__attribute__((address_space(1))) void*)g,
                                   (__attribute__((address_space(3))) void*)l, 16, 0, 0);
}

// ---------------------------------------------------------------- transpose
__launch_bounds__(256, 4)
__global__ void transpose_f32_bf16(const float* __restrict__ in, short* __restrict__ outT,
                                   int R, int C) {
  __shared__ float t[32][33];
  const int c0 = blockIdx.x * 32, r0 = blockIdx.y * 32;
  const int tx = threadIdx.x, ty = threadIdx.y;
#pragma unroll
  for (int i = 0; i < 4; ++i)
    t[ty + 8 * i][tx] = in[(size_t)(r0 + ty + 8 * i) * C + (c0 + tx)];
  __syncthreads();
#pragma unroll
  for (int i = 0; i < 4; ++i)
    outT[(size_t)(c0 + ty + 8 * i) * R + (r0 + tx)] = f2bf(t[tx][ty + 8 * i]);
}

// V [B*2048][1024](bf16) -> Vt [bh][64][2048](bf16)
__launch_bounds__(256, 4)
__global__ void transpose_v(const short* __restrict__ V, short* __restrict__ Vt) {
  __shared__ short t[32][33];
  const int m0 = blockIdx.x * 32;
  const int d0 = blockIdx.y * 32;
  const int bh = blockIdx.z;
  const int b = bh >> 4, h = bh & 15;
  const int tx = threadIdx.x, ty = threadIdx.y;
#pragma unroll
  for (int i = 0; i < 4; ++i)
    t[ty + 8 * i][tx] = V[((size_t)b * 2048 + m0 + ty + 8 * i) * 1024 + h * 64 + d0 + tx];
  __syncthreads();
#pragma unroll
  for (int i = 0; i < 4; ++i)
    Vt[((size_t)bh * 64 + d0 + ty + 8 * i) * 2048 + (m0 + tx)] = t[tx][ty + 8 * i];
}

// ---------------------------------------------------------------- layernorm
__launch_bounds__(256, 4)
__global__ void ln_kernel(const float* __restrict__ in, const float* __restrict__ g,
                          const float* __restrict__ b, short* __restrict__ out) {
  const int row = blockIdx.x;
  const int tid = threadIdx.x;
  const float4 v = ((const float4*)(in + (size_t)row * 1024))[tid];
  float s = v.x + v.y + v.z + v.w;
  float s2 = v.x * v.x + v.y * v.y + v.z * v.z + v.w * v.w;
#pragma unroll
  for (int off = 1; off < 64; off <<= 1) {
    s += __shfl_xor(s, off);
    s2 += __shfl_xor(s2, off);
  }
  __shared__ float ps[4], pq[4];
  const int w = tid >> 6, lane = tid & 63;
  if (lane == 0) { ps[w] = s; pq[w] = s2; }
  __syncthreads();
  s = ps[0] + ps[1] + ps[2] + ps[3];
  s2 = pq[0] + pq[1] + pq[2] + pq[3];
  const float mu = s * (1.f / 1024.f);
  const float rs = rsqrtf(s2 * (1.f / 1024.f) - mu * mu + 1e-5f);
  const float4 gg = ((const float4*)g)[tid];
  const float4 bb = ((const float4*)b)[tid];
  short4 o4;
  o4.x = f2bf((v.x - mu) * rs * gg.x + bb.x);
  o4.y = f2bf((v.y - mu) * rs * gg.y + bb.y);
  o4.z = f2bf((v.z - mu) * rs * gg.z + bb.z);
  o4.w = f2bf((v.w - mu) * rs * gg.w + bb.w);
  ((short4*)(out + (size_t)row * 1024))[tid] = o4;
}

// ---------------------------------------------------------------- GEMM
enum { EPI_Q = 0, EPI_PLAIN = 1, EPI_BIAS_RESID_F32 = 2, EPI_BIAS_SILU = 3 };

template <int EPI>
__launch_bounds__(256, 2)
__global__ void gemm_bt(const short* __restrict__ A, const short* __restrict__ Bt,
                        int N, int K, const float* __restrict__ bias,
                        const float* __restrict__ resid, float scale,
                        short* __restrict__ outb, float* __restrict__ outf) {
  __shared__ short Al[128 * 64];
  __shared__ short Bl[128 * 64];
  const int tid = threadIdx.x;
  const int lane = tid & 63, w = tid >> 6;
  const int wrow = w >> 1, wcol = w & 1;
  const int lg = lane >> 4, lr = lane & 15;
  const int row0 = blockIdx.y * 128, col0 = blockIdx.x * 128;

  f32x4 acc[4][4] = {};

  const int sr = w * 32 + (lane >> 3);
  const int scb = ((lane & 7) * 16) ^ (((lane >> 3) & 7) << 4);
  const int fswz = (lr & 7) << 4;

  for (int kk = 0; kk < K; kk += 64) {
    __syncthreads();
#pragma unroll
    for (int i = 0; i < 4; ++i) {
      const int r = sr + i * 8;
      gload_lds16((const char*)(A + (size_t)(row0 + r) * K + kk) + scb,
                  (char*)Al + (size_t)(w * 32 + i * 8) * 128);
      gload_lds16((const char*)(Bt + (size_t)(col0 + r) * K + kk) + scb,
                  (char*)Bl + (size_t)(w * 32 + i * 8) * 128);
    }
    __syncthreads();
#pragma unroll
    for (int ks = 0; ks < 2; ++ks) {
      bf16x8 af[4], bfr[4];
#pragma unroll
      for (int mi = 0; mi < 4; ++mi) {
        const int r = wrow * 64 + mi * 16 + lr;
        af[mi] = *(const bf16x8*)((const char*)Al + r * 128 + ((ks * 64 + lg * 16) ^ fswz));
      }
#pragma unroll
      for (int ni = 0; ni < 4; ++ni) {
        const int c = wcol * 64 + ni * 16 + lr;
        bfr[ni] = *(const bf16x8*)((const char*)Bl + c * 128 + ((ks * 64 + lg * 16) ^ fswz));
      }
#pragma unroll
      for (int mi = 0; mi < 4; ++mi)
#pragma unroll
        for (int ni = 0; ni < 4; ++ni)
          acc[mi][ni] = __builtin_amdgcn_mfma_f32_16x16x32_bf16(af[mi], bfr[ni], acc[mi][ni], 0, 0, 0);
    }
  }
#pragma unroll
  for (int mi = 0; mi < 4; ++mi) {
#pragma unroll
    for (int ni = 0; ni < 4; ++ni) {
      const int cg = col0 + wcol * 64 + ni * 16 + lr;
#pragma unroll
      for (int r = 0; r < 4; ++r) {
        const int rg = row0 + wrow * 64 + mi * 16 + lg * 4 + r;
        const size_t idx = (size_t)rg * N + cg;
        const float v = acc[mi][ni][r];
        if constexpr (EPI == EPI_Q) {
          outb[idx] = f2bf(v * scale);
        } else if constexpr (EPI == EPI_PLAIN) {
          outb[idx] = f2bf(v);
        } else if constexpr (EPI == EPI_BIAS_RESID_F32) {
          outf[idx] = v + bias[cg] + resid[idx];
        } else {
          const float u = v + bias[cg];
          outb[idx] = f2bf(u / (1.f + __expf(-u)));
        }
      }
    }
  }
}

// ---------------------------------------------------------------- attention
// 8 waves/block, 512 thr. Each wave owns 32 q-rows; block covers 256 q-rows.
// KV tile = 64, K+V staged in double-buffered LDS via global_load_lds
// (pre-swizzled source <-> swizzled ds_read, rule #21). Swapped QK^T
// (mfma(K,Q)) so softmax reduce is per-lane + shfl_xor(16,32). P via
// per-wave swizzled LDS. Defer-max threshold 8 (exp2 domain). Q pre-scaled
// by 1/8*log2(e) in the Q-GEMM epilogue.
__launch_bounds__(512, 4)
__global__ void attn_kernel(const short* __restrict__ Qg, const short* __restrict__ Kg,
                            const short* __restrict__ Vtg, short* __restrict__ AO) {
  __shared__ short Kl[2][64 * 64];
  __shared__ short Vl[2][64 * 64];
  __shared__ short Pl[8][32 * 64];
  const int tid = threadIdx.x;
  const int lane = tid & 63, w = tid >> 6;
  const int lg = lane >> 4, lr = lane & 15;

  // T1: XCD swizzle — each XCD owns 8 heads (K/V working set 4MB, L2-fit).
  const int id = blockIdx.x;           // 512 blocks
  const int xcd = id & 7, j = id >> 3;
  const int bh = xcd * 8 + (j & 7);
  const int qblk = j >> 3;             // 0..7
  const int b = bh >> 4, h = bh & 15;
  const int q0 = qblk * 256 + w * 32;

  // Q fragments (B operand: col=q=lane&15, k=d=(lane>>4)*8+j)
  bf16x8 qf[2][2];
#pragma unroll
  for (int qb = 0; qb < 2; ++qb) {
    const short* qp = Qg + ((size_t)b * 2048 + q0 + qb * 16 + lr) * 1024 + h * 64 + lg * 8;
    qf[qb][0] = *(const bf16x8*)qp;
    qf[qb][1] = *(const bf16x8*)(qp + 32);
  }

  // staging: wave w stages rows w*8..w*8+7 of the 64-row K and V tiles.
  const int srow = lane >> 3;                            // 0..7
  const int scb = ((lane & 7) << 4) ^ (srow << 4);       // pre-swizzled source col-byte
  const char* Ks = (const char*)Kg + ((size_t)b * 2048 + w * 8 + srow) * 2048 + h * 128 + scb;
  const char* Vs = (const char*)Vtg + ((size_t)bh * 64 + w * 8 + srow) * 4096 + scb;
  char* KB[2] = {(char*)&Kl[0][0] + w * 1024, (char*)&Kl[1][0] + w * 1024};
  char* VB[2] = {(char*)&Vl[0][0] + w * 1024, (char*)&Vl[1][0] + w * 1024};

  f32x4 acc[2][4] = {};
  float m_run[2] = {-1e30f, -1e30f};
  float l_run[2] = {0.f, 0.f};
  char* Pw = (char*)&Pl[w][0];
  const int sw = (lr & 7) << 4;

  gload_lds16(Ks, KB[0]);
  gload_lds16(Vs, VB[0]);
  __syncthreads();
  int buf = 0;

  for (int kv0 = 0; kv0 < 2048; kv0 += 64) {
    // prefetch next tile into the other buffer (overlaps this tile's compute)
    if (kv0 + 64 < 2048) {
      gload_lds16(Ks + (size_t)(kv0 + 64) * 2048, KB[buf ^ 1]);
      gload_lds16(Vs + (size_t)(kv0 + 64) * 2, VB[buf ^ 1]);
    }
    // ---- QK^T: St[kv16-tile][qb], lane holds q=lane&15, kv=lg*4+r
    f32x4 st[4][2];
#pragma unroll
    for (int t = 0; t < 4; ++t) {
      const char* kb = (const char*)&Kl[buf][0] + (t * 16 + lr) * 128;
      const bf16x8 kf0 = *(const bf16x8*)(kb + ((lg * 16) ^ sw));
      const bf16x8 kf1 = *(const bf16x8*)(kb + ((64 + lg * 16) ^ sw));
#pragma unroll
      for (int qb = 0; qb < 2; ++qb) {
        f32x4 z = {};
        z = __builtin_amdgcn_mfma_f32_16x16x32_bf16(kf0, qf[qb][0], z, 0, 0, 0);
        z = __builtin_amdgcn_mfma_f32_16x16x32_bf16(kf1, qf[qb][1], z, 0, 0, 0);
        st[t][qb] = z;
      }
    }
    // ---- softmax (online, exp2 domain, defer-max THR=8)
#pragma unroll
    for (int qb = 0; qb < 2; ++qb) {
      float smax = st[0][qb][0];
#pragma unroll
      for (int t = 0; t < 4; ++t)
#pragma unroll
        for (int r = 0; r < 4; ++r) smax = fmaxf(smax, st[t][qb][r]);
      smax = fmaxf(smax, __shfl_xor(smax, 16));
      smax = fmaxf(smax, __shfl_xor(smax, 32));
      float m_use = m_run[qb];
      if (!__all(smax - m_use <= 8.f)) {
        const float mnew = fmaxf(m_use, smax);
        const float alpha = __builtin_amdgcn_exp2f(m_use - mnew);
        m_run[qb] = mnew;
        m_use = mnew;
        l_run[qb] *= alpha;
        float ar[4];
#pragma unroll
        for (int r = 0; r < 4; ++r) ar[r] = __shfl(alpha, lg * 4 + r);
#pragma unroll
        for (int dt = 0; dt < 4; ++dt)
#pragma unroll
          for (int r = 0; r < 4; ++r) acc[qb][dt][r] *= ar[r];
      }
      float rsum = 0.f;
#pragma unroll
      for (int t = 0; t < 4; ++t) {
        bf16x4 pk;
        float ps = 0.f;
#pragma unroll
        for (int r = 0; r < 4; ++r) {
          const float p = __builtin_amdgcn_exp2f(st[t][qb][r] - m_use);
          ps += p;
          pk[r] = (__bf16)p;
        }
        rsum += ps;
        *(bf16x4*)(Pw + (qb * 16 + lr) * 128 + ((t * 32 + lg * 8) ^ sw)) = pk;
      }
      rsum += __shfl_xor(rsum, 16);
      rsum += __shfl_xor(rsum, 32);
      l_run[qb] += rsum;
    }
    // ---- PV: O += P @ V  (P per-wave LDS, V shared LDS)
#pragma unroll
    for (int c = 0; c < 2; ++c) {
      const bf16x8 pf0 = *(const bf16x8*)(Pw + lr * 128 + ((c * 64 + lg * 16) ^ sw));
      const bf16x8 pf1 = *(const bf16x8*)(Pw + (16 + lr) * 128 + ((c * 64 + lg * 16) ^ sw));
#pragma unroll
      for (int dt = 0; dt < 4; ++dt) {
        const bf16x8 vf = *(const bf16x8*)((const char*)&Vl[buf][0] + (dt * 16 + lr) * 128 +
                                           ((c * 64 + lg * 16) ^ sw));
        acc[0][dt] = __builtin_amdgcn_mfma_f32_16x16x32_bf16(pf0, vf, acc[0][dt], 0, 0, 0);
        acc[1][dt] = __builtin_amdgcn_mfma_f32_16x16x32_bf16(pf1, vf, acc[1][dt], 0, 0, 0);
      }
    }
    __syncthreads();
    buf ^= 1;
  }
  // ---- epilogue
#pragma unroll
  for (int qb = 0; qb < 2; ++qb) {
    const float linv = 1.f / l_run[qb];
    float lv[4];
#pragma unroll
    for (int r = 0; r < 4; ++r) lv[r] = __shfl(linv, lg * 4 + r);
#pragma unroll
    for (int dt = 0; dt < 4; ++dt)
#pragma unroll
      for (int r = 0; r < 4; ++r)
        AO[((size_t)b * 2048 + q0 + qb * 16 + lg * 4 + r) * 1024 + h * 64 + dt * 16 + lr] =
            f2bf(acc[qb][dt][r] * lv[r]);
  }
}

// ---------------------------------------------------------------- launch
extern "C" void kernel_launch(void* const* d_in, const int* in_sizes, int n_in,
                              void* d_out, int out_size, void* d_ws, size_t ws_size,
                              hipStream_t stream) {
  const float* x   = (const float*)d_in[0];
  const float* ctx = (const float*)d_in[1];
  const float* Wq  = (const float*)d_in[2];
  const float* Wk  = (const float*)d_in[3];
  const float* Wv  = (const float*)d_in[4];
  const float* Wo  = (const float*)d_in[5];
  const float* bo  = (const float*)d_in[6];
  const float* g_q = (const float*)d_in[7];
  const float* b_q = (const float*)d_in[8];
  const float* g_k = (const float*)d_in[9];
  const float* b_k = (const float*)d_in[10];
  const float* g_m = (const float*)d_in[11];
  const float* b_m = (const float*)d_in[12];
  const float* W1  = (const float*)d_in[13];
  const float* b1  = (const float*)d_in[14];
  const float* W2  = (const float*)d_in[15];
  const float* b2  = (const float*)d_in[16];
  float* out = (float*)d_out;

  short* p = (short*)d_ws;
  short* xn  = p; p += (size_t)8192 * 1024;
  short* cn  = p; p += (size_t)8192 * 1024;
  short* Qb  = p; p += (size_t)8192 * 1024;
  short* Kb  = p; p += (size_t)8192 * 1024;
  short* Vb  = p; p += (size_t)8192 * 1024;
  short* Vts = p; p += (size_t)8192 * 1024;
  short* AO  = p; p += (size_t)8192 * 1024;
  short* hn  = p; p += (size_t)8192 * 1024;
  short* hm  = p; p += (size_t)8192 * 4096;
  short* WqT = p; p += (size_t)1024 * 1024;
  short* WkT = p; p += (size_t)1024 * 1024;
  short* WvT = p; p += (size_t)1024 * 1024;
  short* WoT = p; p += (size_t)1024 * 1024;
  short* W1T = p; p += (size_t)1024 * 4096;
  short* W2T = p; p += (size_t)4096 * 1024;
  float* x2  = (float*)p;  // 8192*1024 fp32

  const dim3 tb(32, 8);
  transpose_f32_bf16<<<dim3(32, 32), tb, 0, stream>>>(Wq, WqT, 1024, 1024);
  transpose_f32_bf16<<<dim3(32, 32), tb, 0, stream>>>(Wk, WkT, 1024, 1024);
  transpose_f32_bf16<<<dim3(32, 32), tb, 0, stream>>>(Wv, WvT, 1024, 1024);
  transpose_f32_bf16<<<dim3(32, 32), tb, 0, stream>>>(Wo, WoT, 1024, 1024);
  transpose_f32_bf16<<<dim3(128, 32), tb, 0, stream>>>(W1, W1T, 1024, 4096);
  transpose_f32_bf16<<<dim3(32, 128), tb, 0, stream>>>(W2, W2T, 4096, 1024);

  ln_kernel<<<8192, 256, 0, stream>>>(x, g_q, b_q, xn);
  ln_kernel<<<8192, 256, 0, stream>>>(ctx, g_k, b_k, cn);

  const float qscale = 0.125f * 1.44269504088896340736f;  // 1/sqrt(64) * log2(e)
  gemm_bt<EPI_Q><<<dim3(8, 64), 256, 0, stream>>>(xn, WqT, 1024, 1024, nullptr, nullptr, qscale, Qb, nullptr);
  gemm_bt<EPI_PLAIN><<<dim3(8, 64), 256, 0, stream>>>(cn, WkT, 1024, 1024, nullptr, nullptr, 0.f, Kb, nullptr);
  gemm_bt<EPI_PLAIN><<<dim3(8, 64), 256, 0, stream>>>(cn, WvT, 1024, 1024, nullptr, nullptr, 0.f, Vb, nullptr);

  transpose_v<<<dim3(64, 2, 64), tb, 0, stream>>>(Vb, Vts);

  attn_kernel<<<512, 512, 0, stream>>>(Qb, Kb, Vts, AO);

  gemm_bt<EPI_BIAS_RESID_F32><<<dim3(8, 64), 256, 0, stream>>>(AO, WoT, 1024, 1024, bo, x, 0.f, nullptr, x2);

  ln_kernel<<<8192, 256, 0, stream>>>(x2, g_m, b_m, hn);

  gemm_bt<EPI_BIAS_SILU><<<dim3(32, 64), 256, 0, stream>>>(hn, W1T, 4096, 1024, b1, nullptr, 0.f, hm, nullptr);
  gemm_bt<EPI_BIAS_RESID_F32><<<dim3(8, 64), 256, 0, stream>>>(hm, W2T, 1024, 4096, b2, x2, 0.f, nullptr, out);
}